// Round 1
// baseline (3131.851 us; speedup 1.0000x reference)
//
#include <hip/hip_runtime.h>
#include <math.h>

#define NN 100000
#define DIN 256
#define DH 128

// ---------------- degree / normalization ----------------
__global__ void k_deg_init(float* __restrict__ deg) {
    int i = blockIdx.x * 256 + threadIdx.x;
    if (i < NN) deg[i] = 1.0f;  // self-loop
}

__global__ void k_deg_count(const int* __restrict__ dst, int E, float* __restrict__ deg) {
    int e = blockIdx.x * 256 + threadIdx.x;
    if (e < E) atomicAdd(&deg[dst[e]], 1.0f);
}

__global__ void k_dinv(float* __restrict__ deg) {
    int i = blockIdx.x * 256 + threadIdx.x;
    if (i < NN) deg[i] = rsqrtf(deg[i]);   // deg >= 1 always
}

// ---------------- layer 1 GEMM: h_scaled = (x @ W1) * dinv[row]; acc1 seeded = h_scaled ----
// block = 256 threads -> 16 rows x 128 cols; thread: col f = tid&127, rows rg*8..rg*8+7
__global__ __launch_bounds__(256) void k_gemm1(const float* __restrict__ x,
                                               const float* __restrict__ W1,
                                               const float* __restrict__ dinv,
                                               float* __restrict__ hs,
                                               float* __restrict__ acc1) {
    __shared__ float ws[64][128];   // 32 KB W1 k-chunk
    __shared__ float xs[16][64];    // 4 KB  x tile
    const int tid = threadIdx.x;
    const int f   = tid & 127;
    const int rg  = tid >> 7;            // 0 or 1
    const int row0 = blockIdx.x * 16;

    float acc[8];
#pragma unroll
    for (int r = 0; r < 8; ++r) acc[r] = 0.0f;

    for (int k0 = 0; k0 < DIN; k0 += 64) {
        __syncthreads();
        // stage W1[k0:k0+64, :] -> ws
        for (int idx = tid * 4; idx < 64 * 128; idx += 1024) {
            int r = idx >> 7, c = idx & 127;
            *(float4*)&ws[r][c] = *(const float4*)&W1[(k0 + r) * DH + c];
        }
        // stage x[row0:row0+16, k0:k0+64] -> xs
        {
            int idx = tid * 4;                 // 1024 floats total
            int r = idx >> 6, c = idx & 63;
            *(float4*)&xs[r][c] = *(const float4*)&x[(long long)(row0 + r) * DIN + k0 + c];
        }
        __syncthreads();
        for (int kk = 0; kk < 64; ++kk) {
            float wv = ws[kk][f];
#pragma unroll
            for (int r = 0; r < 8; ++r)
                acc[r] = fmaf(xs[rg * 8 + r][kk], wv, acc[r]);
        }
    }
#pragma unroll
    for (int r = 0; r < 8; ++r) {
        int row = row0 + rg * 8 + r;
        float v = acc[r] * dinv[row];
        hs  [(long long)row * DH + f] = v;
        acc1[(long long)row * DH + f] = v;   // seed with self-loop term
    }
}

// ---------------- edge aggregation, layer 1: acc1[dst] += hs[src] ----------------
// 32 threads per edge, float4 per thread (128 floats = 32 float4)
__global__ __launch_bounds__(256) void k_agg1(const int* __restrict__ src,
                                              const int* __restrict__ dst, int E,
                                              const float* __restrict__ hs,
                                              float* __restrict__ acc1) {
    long long t = (long long)blockIdx.x * 256 + threadIdx.x;
    long long e = t >> 5;
    if (e >= E) return;
    int c = (int)(t & 31);
    int s = src[e], d = dst[e];
    float4 v = ((const float4*)hs)[(long long)s * 32 + c];
    float* out = acc1 + (long long)d * DH + c * 4;
    atomicAdd(out + 0, v.x);
    atomicAdd(out + 1, v.y);
    atomicAdd(out + 2, v.z);
    atomicAdd(out + 3, v.w);
}

// ---------------- layer 2 linear: one wave per node ----------------
// r = relu(dinv[i]*acc1[i,:] + b1); z = dot(r, W2); zs[i]=acc2[i]=z*dinv[i]
__global__ __launch_bounds__(256) void k_layer2(const float* __restrict__ acc1,
                                                const float* __restrict__ dinv,
                                                const float* __restrict__ b1,
                                                const float* __restrict__ W2,
                                                float* __restrict__ zs,
                                                float* __restrict__ acc2) {
    int wave = (blockIdx.x * 256 + threadIdx.x) >> 6;
    int lane = threadIdx.x & 63;
    if (wave >= NN) return;
    float di = dinv[wave];
    float r0 = fmaf(di, acc1[(long long)wave * DH + lane],      b1[lane]);
    float r1 = fmaf(di, acc1[(long long)wave * DH + 64 + lane], b1[64 + lane]);
    r0 = fmaxf(r0, 0.0f);
    r1 = fmaxf(r1, 0.0f);
    float v = r0 * W2[lane] + r1 * W2[64 + lane];
#pragma unroll
    for (int off = 32; off > 0; off >>= 1) v += __shfl_down(v, off);
    if (lane == 0) {
        float z = v * di;
        zs[wave]   = z;
        acc2[wave] = z;   // seed self-loop
    }
}

// ---------------- edge aggregation, layer 2 (scalar) ----------------
__global__ void k_agg2(const int* __restrict__ src, const int* __restrict__ dst, int E,
                       const float* __restrict__ zs, float* __restrict__ acc2) {
    int e = blockIdx.x * 256 + threadIdx.x;
    if (e < E) atomicAdd(&acc2[dst[e]], zs[src[e]]);
}

// ---------------- epilogue: sigmoid(dinv*acc2 + b2) ----------------
__global__ void k_final(const float* __restrict__ acc2, const float* __restrict__ dinv,
                        const float* __restrict__ b2, float* __restrict__ out) {
    int i = blockIdx.x * 256 + threadIdx.x;
    if (i < NN) {
        float v = fmaf(dinv[i], acc2[i], b2[0]);
        out[i] = 1.0f / (1.0f + __expf(-v));
    }
}

extern "C" void kernel_launch(void* const* d_in, const int* in_sizes, int n_in,
                              void* d_out, int out_size, void* d_ws, size_t ws_size,
                              hipStream_t stream) {
    const float* x  = (const float*)d_in[0];
    const int*   ei = (const int*)d_in[1];
    const float* W1 = (const float*)d_in[2];
    const float* b1 = (const float*)d_in[3];
    const float* W2 = (const float*)d_in[4];
    const float* b2 = (const float*)d_in[5];
    float* out = (float*)d_out;

    const int E = in_sizes[1] / 2;
    const int* src = ei;
    const int* dst = ei + E;

    // workspace layout (floats)
    float* ws   = (float*)d_ws;
    float* deg  = ws;                        // N          (becomes dinv in-place)
    float* hs   = deg + NN;                  // N*128      (offset 400000 B, 16B aligned)
    float* acc1 = hs + (long long)NN * DH;   // N*128
    float* zs   = acc1 + (long long)NN * DH; // N
    float* acc2 = zs + NN;                   // N
    // total ~103.6 MB

    const int nb_nodes = (NN + 255) / 256;
    const int nb_edges = (E + 255) / 256;

    k_deg_init<<<nb_nodes, 256, 0, stream>>>(deg);
    k_deg_count<<<nb_edges, 256, 0, stream>>>(dst, E, deg);
    k_dinv<<<nb_nodes, 256, 0, stream>>>(deg);

    k_gemm1<<<NN / 16, 256, 0, stream>>>(x, W1, deg, hs, acc1);

    long long agg1_threads = (long long)E * 32;
    int nb_agg1 = (int)((agg1_threads + 255) / 256);
    k_agg1<<<nb_agg1, 256, 0, stream>>>(src, dst, E, hs, acc1);

    int nb_l2 = (NN * 64 + 255) / 256;
    k_layer2<<<nb_l2, 256, 0, stream>>>(acc1, deg, b1, W2, zs, acc2);

    k_agg2<<<nb_edges, 256, 0, stream>>>(src, dst, E, zs, acc2);

    k_final<<<nb_nodes, 256, 0, stream>>>(acc2, deg, b2, out);
}

// Round 2
// 603.333 us; speedup vs baseline: 5.1909x; 5.1909x over previous
//
#include <hip/hip_runtime.h>
#include <math.h>

#define NN 100000
#define DIN 256
#define DH 128
#define NCHUNK 98          // ceil(100000/1024)

// ---------------- zero int counters ----------------
__global__ void k_zero(int* __restrict__ p, int n) {
    int i = blockIdx.x * 256 + threadIdx.x;
    if (i < n) p[i] = 0;
}

// ---------------- histogram of dst (in-degree, excluding self-loop) ----------------
__global__ void k_hist(const int* __restrict__ dst, int E, int* __restrict__ cnt) {
    int e = blockIdx.x * 256 + threadIdx.x;
    if (e < E) atomicAdd(&cnt[dst[e]], 1);
}

// ---------------- dinv = rsqrt(1 + indeg) ----------------
__global__ void k_dinv(const int* __restrict__ cnt, float* __restrict__ dinv) {
    int i = blockIdx.x * 256 + threadIdx.x;
    if (i < NN) dinv[i] = rsqrtf(1.0f + (float)cnt[i]);
}

// ---------------- two-level exclusive scan of cnt -> (excl within chunk, chunk sums) ----
__global__ __launch_bounds__(256) void k_scan1(const int* __restrict__ cnt,
                                               int* __restrict__ excl,
                                               int* __restrict__ chunkSums) {
    __shared__ int tmp[256];
    int t = threadIdx.x;
    int base = blockIdx.x * 1024;
    int i0 = base + t * 4;
    int v0 = (i0 + 0 < NN) ? cnt[i0 + 0] : 0;
    int v1 = (i0 + 1 < NN) ? cnt[i0 + 1] : 0;
    int v2 = (i0 + 2 < NN) ? cnt[i0 + 2] : 0;
    int v3 = (i0 + 3 < NN) ? cnt[i0 + 3] : 0;
    int s0 = v0, s1 = s0 + v1, s2 = s1 + v2, s3 = s2 + v3;
    tmp[t] = s3;
    __syncthreads();
    // Hillis-Steele inclusive scan over 256 quad-sums
    for (int off = 1; off < 256; off <<= 1) {
        int val = (t >= off) ? tmp[t - off] : 0;
        __syncthreads();
        tmp[t] += val;
        __syncthreads();
    }
    int prev = (t > 0) ? tmp[t - 1] : 0;   // exclusive prefix of this quad
    if (i0 + 0 < NN) excl[i0 + 0] = prev;
    if (i0 + 1 < NN) excl[i0 + 1] = prev + s0;
    if (i0 + 2 < NN) excl[i0 + 2] = prev + s1;
    if (i0 + 3 < NN) excl[i0 + 3] = prev + s2;
    if (t == 255) chunkSums[blockIdx.x] = tmp[255];
}

__global__ __launch_bounds__(128) void k_scan2(const int* __restrict__ chunkSums,
                                               int* __restrict__ chunkOff) {
    __shared__ int tmp[128];
    int t = threadIdx.x;
    tmp[t] = (t < NCHUNK) ? chunkSums[t] : 0;
    __syncthreads();
    for (int off = 1; off < 128; off <<= 1) {
        int val = (t >= off) ? tmp[t - off] : 0;
        __syncthreads();
        tmp[t] += val;
        __syncthreads();
    }
    chunkOff[t] = (t > 0) ? tmp[t - 1] : 0;  // exclusive
}

// ---------------- scatter edges into CSR slots ----------------
__global__ void k_fill(const int* __restrict__ src, const int* __restrict__ dst, int E,
                       const int* __restrict__ excl, const int* __restrict__ chunkOff,
                       int* __restrict__ cnt2, int* __restrict__ eidx) {
    int e = blockIdx.x * 256 + threadIdx.x;
    if (e >= E) return;
    int d = dst[e];
    int slot = excl[d] + chunkOff[d >> 10] + atomicAdd(&cnt2[d], 1);
    eidx[slot] = src[e];
}

// ---------------- layer 1 GEMM: hs = (x @ W1) * dinv[row] ----------------
__global__ __launch_bounds__(256) void k_gemm1(const float* __restrict__ x,
                                               const float* __restrict__ W1,
                                               const float* __restrict__ dinv,
                                               float* __restrict__ hs) {
    __shared__ float ws[64][128];
    __shared__ float xs[16][64];
    const int tid = threadIdx.x;
    const int f   = tid & 127;
    const int rg  = tid >> 7;
    const int row0 = blockIdx.x * 16;

    float acc[8];
#pragma unroll
    for (int r = 0; r < 8; ++r) acc[r] = 0.0f;

    for (int k0 = 0; k0 < DIN; k0 += 64) {
        __syncthreads();
        for (int idx = tid * 4; idx < 64 * 128; idx += 1024) {
            int r = idx >> 7, c = idx & 127;
            *(float4*)&ws[r][c] = *(const float4*)&W1[(k0 + r) * DH + c];
        }
        {
            int idx = tid * 4;
            int r = idx >> 6, c = idx & 63;
            *(float4*)&xs[r][c] = *(const float4*)&x[(long long)(row0 + r) * DIN + k0 + c];
        }
        __syncthreads();
        for (int kk = 0; kk < 64; ++kk) {
            float wv = ws[kk][f];
#pragma unroll
            for (int r = 0; r < 8; ++r)
                acc[r] = fmaf(xs[rg * 8 + r][kk], wv, acc[r]);
        }
    }
#pragma unroll
    for (int r = 0; r < 8; ++r) {
        int row = row0 + rg * 8 + r;
        hs[(long long)row * DH + f] = acc[r] * dinv[row];
    }
}

// ---------------- layer-1 aggregation via CSR: one wave per node ----------------
__global__ __launch_bounds__(256) void k_agg1_csr(const int* __restrict__ eidx,
                                                  const int* __restrict__ excl,
                                                  const int* __restrict__ chunkOff,
                                                  const int* __restrict__ cnt,
                                                  const float* __restrict__ hs,
                                                  float* __restrict__ acc1) {
    int w = (blockIdx.x * 256 + threadIdx.x) >> 6;
    if (w >= NN) return;
    int lane = threadIdx.x & 63;
    int offs = excl[w] + chunkOff[w >> 10];
    int c = cnt[w];
    const float2* hs2 = (const float2*)hs;
    float2 acc = hs2[(long long)w * 64 + lane];   // self-loop term
    int j = 0;
    for (; j + 1 < c; j += 2) {
        int s0 = eidx[offs + j];
        int s1 = eidx[offs + j + 1];
        float2 v0 = hs2[(long long)s0 * 64 + lane];
        float2 v1 = hs2[(long long)s1 * 64 + lane];
        acc.x += v0.x + v1.x;
        acc.y += v0.y + v1.y;
    }
    if (j < c) {
        int s0 = eidx[offs + j];
        float2 v0 = hs2[(long long)s0 * 64 + lane];
        acc.x += v0.x;
        acc.y += v0.y;
    }
    ((float2*)acc1)[(long long)w * 64 + lane] = acc;
}

// ---------------- layer 2 linear: one wave per node ----------------
__global__ __launch_bounds__(256) void k_layer2(const float* __restrict__ acc1,
                                                const float* __restrict__ dinv,
                                                const float* __restrict__ b1,
                                                const float* __restrict__ W2,
                                                float* __restrict__ zs) {
    int wave = (blockIdx.x * 256 + threadIdx.x) >> 6;
    int lane = threadIdx.x & 63;
    if (wave >= NN) return;
    float di = dinv[wave];
    float r0 = fmaf(di, acc1[(long long)wave * DH + lane],      b1[lane]);
    float r1 = fmaf(di, acc1[(long long)wave * DH + 64 + lane], b1[64 + lane]);
    r0 = fmaxf(r0, 0.0f);
    r1 = fmaxf(r1, 0.0f);
    float v = r0 * W2[lane] + r1 * W2[64 + lane];
#pragma unroll
    for (int off = 32; off > 0; off >>= 1) v += __shfl_down(v, off);
    if (lane == 0) zs[wave] = v * di;
}

// ---------------- layer-2 aggregation + sigmoid epilogue: one thread per node ----------------
__global__ void k_agg2_final(const int* __restrict__ eidx,
                             const int* __restrict__ excl,
                             const int* __restrict__ chunkOff,
                             const int* __restrict__ cnt,
                             const float* __restrict__ zs,
                             const float* __restrict__ dinv,
                             const float* __restrict__ b2,
                             float* __restrict__ out) {
    int i = blockIdx.x * 256 + threadIdx.x;
    if (i >= NN) return;
    int offs = excl[i] + chunkOff[i >> 10];
    int c = cnt[i];
    float v = zs[i];   // self-loop
    for (int j = 0; j < c; ++j) v += zs[eidx[offs + j]];
    float z = fmaf(dinv[i], v, b2[0]);
    out[i] = 1.0f / (1.0f + __expf(-z));
}

extern "C" void kernel_launch(void* const* d_in, const int* in_sizes, int n_in,
                              void* d_out, int out_size, void* d_ws, size_t ws_size,
                              hipStream_t stream) {
    const float* x  = (const float*)d_in[0];
    const int*   ei = (const int*)d_in[1];
    const float* W1 = (const float*)d_in[2];
    const float* b1 = (const float*)d_in[3];
    const float* W2 = (const float*)d_in[4];
    const float* b2 = (const float*)d_in[5];
    float* out = (float*)d_out;

    const int E = in_sizes[1] / 2;
    const int* src = ei;
    const int* dst = ei + E;

    // workspace layout (4-byte elements)
    char* wsb = (char*)d_ws;
    float* dinv    = (float*)wsb;                       // N
    int*   cnt     = (int*)(dinv + NN);                 // N
    int*   cnt2    = cnt + NN;                          // N
    int*   excl    = cnt2 + NN;                         // N
    int*   chunkS  = excl + NN;                         // 128
    int*   chunkO  = chunkS + 128;                      // 128
    int*   eidx    = chunkO + 128;                      // E
    float* hs      = (float*)(eidx + E);                // N*128
    float* acc1    = hs + (long long)NN * DH;           // N*128
    float* zs      = acc1 + (long long)NN * DH;         // N
    // total ~ 111 MB

    const int nb_nodes = (NN + 255) / 256;
    const int nb_edges = (E + 255) / 256;

    k_zero<<<(2 * NN + 255) / 256, 256, 0, stream>>>(cnt, 2 * NN);  // cnt + cnt2 contiguous
    k_hist<<<nb_edges, 256, 0, stream>>>(dst, E, cnt);
    k_dinv<<<nb_nodes, 256, 0, stream>>>(cnt, dinv);
    k_scan1<<<NCHUNK, 256, 0, stream>>>(cnt, excl, chunkS);
    k_scan2<<<1, 128, 0, stream>>>(chunkS, chunkO);
    k_fill<<<nb_edges, 256, 0, stream>>>(src, dst, E, excl, chunkO, cnt2, eidx);

    k_gemm1<<<NN / 16, 256, 0, stream>>>(x, W1, dinv, hs);

    k_agg1_csr<<<(NN * 64 + 255) / 256, 256, 0, stream>>>(eidx, excl, chunkO, cnt, hs, acc1);

    k_layer2<<<(NN * 64 + 255) / 256, 256, 0, stream>>>(acc1, dinv, b1, W2, zs);

    k_agg2_final<<<nb_nodes, 256, 0, stream>>>(eidx, excl, chunkO, cnt, zs, dinv, b2, out);
}

// Round 3
// 426.275 us; speedup vs baseline: 7.3470x; 1.4154x over previous
//
#include <hip/hip_runtime.h>
#include <math.h>

#define NN 100000
#define DIN 256
#define DH 128
#define NCHUNK 98          // ceil(100000/1024)

using short8  = __attribute__((ext_vector_type(8))) short;
using float4v = __attribute__((ext_vector_type(4))) float;

static __device__ __forceinline__ unsigned short f2bf(float f) {
    unsigned u = __float_as_uint(f);
    unsigned r = u + 0x7fffu + ((u >> 16) & 1u);   // round-to-nearest-even
    return (unsigned short)(r >> 16);
}

// ---------------- zero int counters ----------------
__global__ void k_zero(int* __restrict__ p, int n) {
    int i = blockIdx.x * 256 + threadIdx.x;
    if (i < n) p[i] = 0;
}

// ---------------- histogram of dst (in-degree, excluding self-loop) ----------------
__global__ void k_hist(const int* __restrict__ dst, int E, int* __restrict__ cnt) {
    int e = blockIdx.x * 256 + threadIdx.x;
    if (e < E) atomicAdd(&cnt[dst[e]], 1);
}

// ---------------- dinv = rsqrt(1 + indeg) ----------------
__global__ void k_dinv(const int* __restrict__ cnt, float* __restrict__ dinv) {
    int i = blockIdx.x * 256 + threadIdx.x;
    if (i < NN) dinv[i] = rsqrtf(1.0f + (float)cnt[i]);
}

// ---------------- two-level exclusive scan ----------------
__global__ __launch_bounds__(256) void k_scan1(const int* __restrict__ cnt,
                                               int* __restrict__ excl,
                                               int* __restrict__ chunkSums) {
    __shared__ int tmp[256];
    int t = threadIdx.x;
    int base = blockIdx.x * 1024;
    int i0 = base + t * 4;
    int v0 = (i0 + 0 < NN) ? cnt[i0 + 0] : 0;
    int v1 = (i0 + 1 < NN) ? cnt[i0 + 1] : 0;
    int v2 = (i0 + 2 < NN) ? cnt[i0 + 2] : 0;
    int v3 = (i0 + 3 < NN) ? cnt[i0 + 3] : 0;
    int s0 = v0, s1 = s0 + v1, s2 = s1 + v2, s3 = s2 + v3;
    tmp[t] = s3;
    __syncthreads();
    for (int off = 1; off < 256; off <<= 1) {
        int val = (t >= off) ? tmp[t - off] : 0;
        __syncthreads();
        tmp[t] += val;
        __syncthreads();
    }
    int prev = (t > 0) ? tmp[t - 1] : 0;
    if (i0 + 0 < NN) excl[i0 + 0] = prev;
    if (i0 + 1 < NN) excl[i0 + 1] = prev + s0;
    if (i0 + 2 < NN) excl[i0 + 2] = prev + s1;
    if (i0 + 3 < NN) excl[i0 + 3] = prev + s2;
    if (t == 255) chunkSums[blockIdx.x] = tmp[255];
}

__global__ __launch_bounds__(128) void k_scan2(const int* __restrict__ chunkSums,
                                               int* __restrict__ chunkOff) {
    __shared__ int tmp[128];
    int t = threadIdx.x;
    tmp[t] = (t < NCHUNK) ? chunkSums[t] : 0;
    __syncthreads();
    for (int off = 1; off < 128; off <<= 1) {
        int val = (t >= off) ? tmp[t - off] : 0;
        __syncthreads();
        tmp[t] += val;
        __syncthreads();
    }
    chunkOff[t] = (t > 0) ? tmp[t - 1] : 0;
}

// ---------------- scatter edges into CSR slots ----------------
__global__ void k_fill(const int* __restrict__ src, const int* __restrict__ dst, int E,
                       const int* __restrict__ excl, const int* __restrict__ chunkOff,
                       int* __restrict__ cnt2, int* __restrict__ eidx) {
    int e = blockIdx.x * 256 + threadIdx.x;
    if (e >= E) return;
    int d = dst[e];
    int slot = excl[d] + chunkOff[d >> 10] + atomicAdd(&cnt2[d], 1);
    eidx[slot] = src[e];
}

// ---------------- layer 1 GEMM (MFMA bf16): hs_bf16 = (x @ W1) * dinv[row] ----------------
// block = 256 = 4 waves; block computes 64 rows x 128 cols; wave w handles cols w*32..w*32+31.
// W1 fragments live in registers (K=256 fully resident); A staged in LDS bf16, XOR-swizzled.
__global__ __launch_bounds__(256) void k_gemm1(const float* __restrict__ x,
                                               const float* __restrict__ W1,
                                               const float* __restrict__ dinv,
                                               unsigned short* __restrict__ hs) {
    // A tile: 64 rows x 256 k, stored as 16B chunks: chunk(row,kb) at row*32 + (kb ^ (row&31))
    __shared__ unsigned short aL[64 * 32 * 8];   // 32 KB
    const int tid  = threadIdx.x;
    const int wave = tid >> 6;
    const int lane = tid & 63;
    const int quad = lane >> 4;
    const int m16  = lane & 15;
    const int row0 = blockIdx.x * 64;
    const int n0   = wave * 32;

    // ---- load W1 fragments into registers: b[nt][ks], nt in {0,1}, ks in 0..7 ----
    short8 bfr[2][8];
#pragma unroll
    for (int ks = 0; ks < 8; ++ks) {
#pragma unroll
        for (int nt = 0; nt < 2; ++nt) {
            short8 v;
            int n = n0 + nt * 16 + m16;
#pragma unroll
            for (int j = 0; j < 8; ++j) {
                float w = W1[(ks * 32 + quad * 8 + j) * DH + n];
                v[j] = (short)f2bf(w);
            }
            bfr[nt][ks] = v;
        }
    }

    // ---- stage A: x[row0:row0+64, 0:256] -> bf16 LDS, swizzled ----
#pragma unroll
    for (int it = 0; it < 8; ++it) {
        int id  = it * 256 + tid;          // 0..2047
        int row = id >> 5;                 // 0..63
        int kb  = id & 31;                 // 16B chunk index along K
        int gr  = row0 + row;
        float4 f0, f1;
        if (gr < NN) {
            const float* xp = &x[(long long)gr * DIN + kb * 8];
            f0 = *(const float4*)xp;
            f1 = *(const float4*)(xp + 4);
        } else {
            f0 = make_float4(0.f, 0.f, 0.f, 0.f);
            f1 = f0;
        }
        short8 v;
        v[0] = (short)f2bf(f0.x); v[1] = (short)f2bf(f0.y);
        v[2] = (short)f2bf(f0.z); v[3] = (short)f2bf(f0.w);
        v[4] = (short)f2bf(f1.x); v[5] = (short)f2bf(f1.y);
        v[6] = (short)f2bf(f1.z); v[7] = (short)f2bf(f1.w);
        int chunk = row * 32 + (kb ^ (row & 31));
        *(short8*)&aL[chunk * 8] = v;
    }
    __syncthreads();

    // ---- MFMA main loop: 4 m-tiles x 2 n-tiles x 8 k-steps ----
    float4v acc[4][2];
#pragma unroll
    for (int mt = 0; mt < 4; ++mt)
#pragma unroll
        for (int nt = 0; nt < 2; ++nt)
            acc[mt][nt] = (float4v)(0.0f);

#pragma unroll
    for (int mt = 0; mt < 4; ++mt) {
        int row = mt * 16 + m16;
#pragma unroll
        for (int ks = 0; ks < 8; ++ks) {
            int kb = ks * 4 + quad;
            int chunk = row * 32 + (kb ^ (row & 31));
            short8 a = *(const short8*)&aL[chunk * 8];
            acc[mt][0] = __builtin_amdgcn_mfma_f32_16x16x32_bf16(a, bfr[0][ks], acc[mt][0], 0, 0, 0);
            acc[mt][1] = __builtin_amdgcn_mfma_f32_16x16x32_bf16(a, bfr[1][ks], acc[mt][1], 0, 0, 0);
        }
    }

    // ---- epilogue: *dinv[row], convert bf16, store ----
    // C/D layout: col = lane&15, row_in_tile = quad*4 + r
#pragma unroll
    for (int mt = 0; mt < 4; ++mt) {
#pragma unroll
        for (int r = 0; r < 4; ++r) {
            int row = row0 + mt * 16 + quad * 4 + r;
            if (row < NN) {
                float di = dinv[row];
#pragma unroll
                for (int nt = 0; nt < 2; ++nt) {
                    float v = acc[mt][nt][r] * di;
                    hs[(long long)row * DH + n0 + nt * 16 + m16] = f2bf(v);
                }
            }
        }
    }
}

// ---------------- fused layer-1 aggregation + layer-2 linear: one wave per node ----------------
// acc = sum over {self} U in-neighbors of hs[s] (bf16->fp32); then
// r = relu(dinv*acc + b1); z = dot(r, W2) * dinv -> zs
__global__ __launch_bounds__(256) void k_agg1l2(const int* __restrict__ eidx,
                                                const int* __restrict__ excl,
                                                const int* __restrict__ chunkOff,
                                                const int* __restrict__ cnt,
                                                const unsigned* __restrict__ hs2,  // 64 uints/row
                                                const float* __restrict__ dinv,
                                                const float* __restrict__ b1,
                                                const float* __restrict__ W2,
                                                float* __restrict__ zs) {
    int w = (blockIdx.x * 256 + threadIdx.x) >> 6;
    if (w >= NN) return;
    int lane = threadIdx.x & 63;
    int offs = excl[w] + chunkOff[w >> 10];
    int c = cnt[w];

    unsigned u = hs2[(long long)w * 64 + lane];   // self-loop
    float ax = __uint_as_float(u << 16);
    float ay = __uint_as_float(u & 0xffff0000u);

    int j = 0;
    for (; j + 3 < c; j += 4) {
        int s0 = eidx[offs + j + 0];
        int s1 = eidx[offs + j + 1];
        int s2 = eidx[offs + j + 2];
        int s3 = eidx[offs + j + 3];
        unsigned u0 = hs2[(long long)s0 * 64 + lane];
        unsigned u1 = hs2[(long long)s1 * 64 + lane];
        unsigned u2 = hs2[(long long)s2 * 64 + lane];
        unsigned u3 = hs2[(long long)s3 * 64 + lane];
        ax += __uint_as_float(u0 << 16) + __uint_as_float(u1 << 16)
            + __uint_as_float(u2 << 16) + __uint_as_float(u3 << 16);
        ay += __uint_as_float(u0 & 0xffff0000u) + __uint_as_float(u1 & 0xffff0000u)
            + __uint_as_float(u2 & 0xffff0000u) + __uint_as_float(u3 & 0xffff0000u);
    }
    for (; j < c; ++j) {
        int s = eidx[offs + j];
        unsigned us = hs2[(long long)s * 64 + lane];
        ax += __uint_as_float(us << 16);
        ay += __uint_as_float(us & 0xffff0000u);
    }

    float di = dinv[w];
    float2 bb = ((const float2*)b1)[lane];
    float2 ww = ((const float2*)W2)[lane];
    float r0 = fmaxf(fmaf(di, ax, bb.x), 0.0f);
    float r1 = fmaxf(fmaf(di, ay, bb.y), 0.0f);
    float v = r0 * ww.x + r1 * ww.y;
#pragma unroll
    for (int off = 32; off > 0; off >>= 1) v += __shfl_down(v, off);
    if (lane == 0) zs[w] = v * di;
}

// ---------------- layer-2 aggregation + sigmoid epilogue: one thread per node ----------------
__global__ void k_agg2_final(const int* __restrict__ eidx,
                             const int* __restrict__ excl,
                             const int* __restrict__ chunkOff,
                             const int* __restrict__ cnt,
                             const float* __restrict__ zs,
                             const float* __restrict__ dinv,
                             const float* __restrict__ b2,
                             float* __restrict__ out) {
    int i = blockIdx.x * 256 + threadIdx.x;
    if (i >= NN) return;
    int offs = excl[i] + chunkOff[i >> 10];
    int c = cnt[i];
    float v = zs[i];   // self-loop
    for (int j = 0; j < c; ++j) v += zs[eidx[offs + j]];
    float z = fmaf(dinv[i], v, b2[0]);
    out[i] = 1.0f / (1.0f + __expf(-z));
}

extern "C" void kernel_launch(void* const* d_in, const int* in_sizes, int n_in,
                              void* d_out, int out_size, void* d_ws, size_t ws_size,
                              hipStream_t stream) {
    const float* x  = (const float*)d_in[0];
    const int*   ei = (const int*)d_in[1];
    const float* W1 = (const float*)d_in[2];
    const float* b1 = (const float*)d_in[3];
    const float* W2 = (const float*)d_in[4];
    const float* b2 = (const float*)d_in[5];
    float* out = (float*)d_out;

    const int E = in_sizes[1] / 2;
    const int* src = ei;
    const int* dst = ei + E;

    // workspace layout (4-byte elements)
    char* wsb = (char*)d_ws;
    float* dinv    = (float*)wsb;                       // N
    int*   cnt     = (int*)(dinv + NN);                 // N
    int*   cnt2    = cnt + NN;                          // N
    int*   excl    = cnt2 + NN;                         // N
    float* zs      = (float*)(excl + NN);               // N
    int*   chunkS  = (int*)(zs + NN);                   // 128
    int*   chunkO  = chunkS + 128;                      // 128
    int*   eidx    = chunkO + 128;                      // E
    unsigned short* hs = (unsigned short*)(eidx + E);   // N*128 bf16 (~25.6 MB)
    // total ~ 34 MB

    const int nb_nodes = (NN + 255) / 256;
    const int nb_edges = (E + 255) / 256;

    k_zero<<<(2 * NN + 255) / 256, 256, 0, stream>>>(cnt, 2 * NN);  // cnt + cnt2
    k_hist<<<nb_edges, 256, 0, stream>>>(dst, E, cnt);
    k_dinv<<<nb_nodes, 256, 0, stream>>>(cnt, dinv);
    k_scan1<<<NCHUNK, 256, 0, stream>>>(cnt, excl, chunkS);
    k_scan2<<<1, 128, 0, stream>>>(chunkS, chunkO);
    k_fill<<<nb_edges, 256, 0, stream>>>(src, dst, E, excl, chunkO, cnt2, eidx);

    k_gemm1<<<(NN + 63) / 64, 256, 0, stream>>>(x, W1, dinv, hs);

    k_agg1l2<<<(NN * 64 + 255) / 256, 256, 0, stream>>>(eidx, excl, chunkO, cnt,
                                                        (const unsigned*)hs, dinv, b1, W2, zs);

    k_agg2_final<<<nb_nodes, 256, 0, stream>>>(eidx, excl, chunkO, cnt, zs, dinv, b2, out);
}

// Round 4
// 405.019 us; speedup vs baseline: 7.7326x; 1.0525x over previous
//
#include <hip/hip_runtime.h>
#include <math.h>

#define NN 100000
#define DIN 256
#define DH 128
#define NCHUNK 98          // ceil(100000/1024)
#define GEMM_NB 1563       // ceil(NN/64)
#define GEMM_NB1 512       // gemm blocks overlapped with hist
#define GEMM_NB2 (GEMM_NB - GEMM_NB1)

using short8  = __attribute__((ext_vector_type(8))) short;
using float4v = __attribute__((ext_vector_type(4))) float;

static __device__ __forceinline__ unsigned short f2bf(float f) {
    unsigned u = __float_as_uint(f);
    unsigned r = u + 0x7fffu + ((u >> 16) & 1u);   // round-to-nearest-even
    return (unsigned short)(r >> 16);
}
static __device__ __forceinline__ float bf_lo(unsigned u) { return __uint_as_float(u << 16); }
static __device__ __forceinline__ float bf_hi(unsigned u) { return __uint_as_float(u & 0xffff0000u); }

// ---------------- GEMM body (MFMA bf16): hs_bf16 = x @ W1 (UNSCALED) ----------------
// One call computes 64 rows x 128 cols; 4 waves, wave w -> cols w*32..w*32+31.
static __device__ __forceinline__ void gemm_body(int gb, const float* __restrict__ x,
                                                 const float* __restrict__ W1,
                                                 unsigned short* __restrict__ hs) {
    __shared__ unsigned short aL[64 * 32 * 8];   // 32 KB, 16B-chunk XOR swizzle
    const int tid  = threadIdx.x;
    const int wave = tid >> 6;
    const int lane = tid & 63;
    const int quad = lane >> 4;
    const int m16  = lane & 15;
    const int row0 = gb * 64;
    const int n0   = wave * 32;

    // W1 fragments in registers (K=256 resident)
    short8 bfr[2][8];
#pragma unroll
    for (int ks = 0; ks < 8; ++ks) {
#pragma unroll
        for (int nt = 0; nt < 2; ++nt) {
            short8 v;
            int n = n0 + nt * 16 + m16;
#pragma unroll
            for (int j = 0; j < 8; ++j) {
                float w = W1[(ks * 32 + quad * 8 + j) * DH + n];
                v[j] = (short)f2bf(w);
            }
            bfr[nt][ks] = v;
        }
    }

    // stage A tile -> bf16 LDS, swizzled
#pragma unroll
    for (int it = 0; it < 8; ++it) {
        int id  = it * 256 + tid;
        int row = id >> 5;
        int kb  = id & 31;
        int gr  = row0 + row;
        float4 f0, f1;
        if (gr < NN) {
            const float* xp = &x[(long long)gr * DIN + kb * 8];
            f0 = *(const float4*)xp;
            f1 = *(const float4*)(xp + 4);
        } else {
            f0 = make_float4(0.f, 0.f, 0.f, 0.f);
            f1 = f0;
        }
        short8 v;
        v[0] = (short)f2bf(f0.x); v[1] = (short)f2bf(f0.y);
        v[2] = (short)f2bf(f0.z); v[3] = (short)f2bf(f0.w);
        v[4] = (short)f2bf(f1.x); v[5] = (short)f2bf(f1.y);
        v[6] = (short)f2bf(f1.z); v[7] = (short)f2bf(f1.w);
        int chunk = row * 32 + (kb ^ (row & 31));
        *(short8*)&aL[chunk * 8] = v;
    }
    __syncthreads();

    float4v acc[4][2];
#pragma unroll
    for (int mt = 0; mt < 4; ++mt)
#pragma unroll
        for (int nt = 0; nt < 2; ++nt)
            acc[mt][nt] = (float4v)(0.0f);

#pragma unroll
    for (int mt = 0; mt < 4; ++mt) {
        int row = mt * 16 + m16;
#pragma unroll
        for (int ks = 0; ks < 8; ++ks) {
            int kb = ks * 4 + quad;
            int chunk = row * 32 + (kb ^ (row & 31));
            short8 a = *(const short8*)&aL[chunk * 8];
            acc[mt][0] = __builtin_amdgcn_mfma_f32_16x16x32_bf16(a, bfr[0][ks], acc[mt][0], 0, 0, 0);
            acc[mt][1] = __builtin_amdgcn_mfma_f32_16x16x32_bf16(a, bfr[1][ks], acc[mt][1], 0, 0, 0);
        }
    }

    // epilogue: store unscaled bf16. C/D layout: col = lane&15, row = quad*4 + r
#pragma unroll
    for (int mt = 0; mt < 4; ++mt) {
#pragma unroll
        for (int r = 0; r < 4; ++r) {
            int row = row0 + mt * 16 + quad * 4 + r;
            if (row < NN) {
#pragma unroll
                for (int nt = 0; nt < 2; ++nt)
                    hs[(long long)row * DH + n0 + nt * 16 + m16] = f2bf(acc[mt][nt][r]);
            }
        }
    }
}

// ---------------- K1: gemm part-A  ||  dst histogram ----------------
__global__ __launch_bounds__(256) void k_gemm_hist(const float* __restrict__ x,
                                                   const float* __restrict__ W1,
                                                   unsigned short* __restrict__ hs,
                                                   const int* __restrict__ dst, int E,
                                                   int* __restrict__ cnt) {
    if ((int)blockIdx.x < GEMM_NB1) { gemm_body(blockIdx.x, x, W1, hs); return; }
    int e = ((int)blockIdx.x - GEMM_NB1) * 256 + threadIdx.x;
    if (e < E) atomicAdd(&cnt[dst[e]], 1);
}

// ---------------- scan level 1 + dinv fused ----------------
__global__ __launch_bounds__(256) void k_scan1d(const int* __restrict__ cnt,
                                                int* __restrict__ excl,
                                                int* __restrict__ chunkSums,
                                                float* __restrict__ dinv) {
    __shared__ int tmp[256];
    int t = threadIdx.x;
    int i0 = blockIdx.x * 1024 + t * 4;
    int v0 = (i0 + 0 < NN) ? cnt[i0 + 0] : 0;
    int v1 = (i0 + 1 < NN) ? cnt[i0 + 1] : 0;
    int v2 = (i0 + 2 < NN) ? cnt[i0 + 2] : 0;
    int v3 = (i0 + 3 < NN) ? cnt[i0 + 3] : 0;
    int s0 = v0, s1 = s0 + v1, s2 = s1 + v2, s3 = s2 + v3;
    tmp[t] = s3;
    __syncthreads();
    for (int off = 1; off < 256; off <<= 1) {
        int val = (t >= off) ? tmp[t - off] : 0;
        __syncthreads();
        tmp[t] += val;
        __syncthreads();
    }
    int prev = (t > 0) ? tmp[t - 1] : 0;
    if (i0 + 0 < NN) { excl[i0 + 0] = prev;      dinv[i0 + 0] = rsqrtf(1.0f + (float)v0); }
    if (i0 + 1 < NN) { excl[i0 + 1] = prev + s0; dinv[i0 + 1] = rsqrtf(1.0f + (float)v1); }
    if (i0 + 2 < NN) { excl[i0 + 2] = prev + s1; dinv[i0 + 2] = rsqrtf(1.0f + (float)v2); }
    if (i0 + 3 < NN) { excl[i0 + 3] = prev + s2; dinv[i0 + 3] = rsqrtf(1.0f + (float)v3); }
    if (t == 255) chunkSums[blockIdx.x] = tmp[255];
}

__global__ __launch_bounds__(128) void k_scan2(const int* __restrict__ chunkSums,
                                               int* __restrict__ chunkOff) {
    __shared__ int tmp[128];
    int t = threadIdx.x;
    tmp[t] = (t < NCHUNK) ? chunkSums[t] : 0;
    __syncthreads();
    for (int off = 1; off < 128; off <<= 1) {
        int val = (t >= off) ? tmp[t - off] : 0;
        __syncthreads();
        tmp[t] += val;
        __syncthreads();
    }
    chunkOff[t] = (t > 0) ? tmp[t - 1] : 0;
}

// ---------------- K4: gemm part-B  ||  CSR fill ----------------
__global__ __launch_bounds__(256) void k_gemm_fill(const float* __restrict__ x,
                                                   const float* __restrict__ W1,
                                                   unsigned short* __restrict__ hs,
                                                   const int* __restrict__ src,
                                                   const int* __restrict__ dst, int E,
                                                   const int* __restrict__ excl,
                                                   const int* __restrict__ chunkOff,
                                                   int* __restrict__ cnt2,
                                                   int* __restrict__ eidx) {
    if ((int)blockIdx.x < GEMM_NB2) { gemm_body(GEMM_NB1 + blockIdx.x, x, W1, hs); return; }
    int e = ((int)blockIdx.x - GEMM_NB2) * 256 + threadIdx.x;
    if (e >= E) return;
    int d = dst[e];
    int slot = excl[d] + chunkOff[d >> 10] + atomicAdd(&cnt2[d], 1);
    eidx[slot] = src[e];
}

// ---------------- fused layer-1 aggregation + layer-2 linear: one wave per node ----------------
// acc = dinv[w]*h[w] + sum_s dinv[s]*h[s]; r = relu(dinv[w]*acc + b1); zs = dot(r,W2)*dinv[w]
__global__ __launch_bounds__(256) void k_agg1l2(const int* __restrict__ eidx,
                                                const int* __restrict__ excl,
                                                const int* __restrict__ chunkOff,
                                                const int* __restrict__ cnt,
                                                const unsigned* __restrict__ hs2,  // 64 uints/row
                                                const float* __restrict__ dinv,
                                                const float* __restrict__ b1,
                                                const float* __restrict__ W2,
                                                float* __restrict__ zs) {
    int w = (blockIdx.x * 256 + threadIdx.x) >> 6;
    if (w >= NN) return;
    int lane = threadIdx.x & 63;
    int offs = excl[w] + chunkOff[w >> 10];
    int c = cnt[w];

    float dw = dinv[w];
    unsigned u = hs2[(long long)w * 64 + lane];   // self-loop
    float ax = dw * bf_lo(u);
    float ay = dw * bf_hi(u);

    int j = 0;
    for (; j + 3 < c; j += 4) {
        int s0 = eidx[offs + j + 0];
        int s1 = eidx[offs + j + 1];
        int s2 = eidx[offs + j + 2];
        int s3 = eidx[offs + j + 3];
        float e0 = dinv[s0], e1 = dinv[s1], e2 = dinv[s2], e3 = dinv[s3];
        unsigned u0 = hs2[(long long)s0 * 64 + lane];
        unsigned u1 = hs2[(long long)s1 * 64 + lane];
        unsigned u2 = hs2[(long long)s2 * 64 + lane];
        unsigned u3 = hs2[(long long)s3 * 64 + lane];
        ax = fmaf(e0, bf_lo(u0), ax); ay = fmaf(e0, bf_hi(u0), ay);
        ax = fmaf(e1, bf_lo(u1), ax); ay = fmaf(e1, bf_hi(u1), ay);
        ax = fmaf(e2, bf_lo(u2), ax); ay = fmaf(e2, bf_hi(u2), ay);
        ax = fmaf(e3, bf_lo(u3), ax); ay = fmaf(e3, bf_hi(u3), ay);
    }
    for (; j < c; ++j) {
        int s = eidx[offs + j];
        float es = dinv[s];
        unsigned us = hs2[(long long)s * 64 + lane];
        ax = fmaf(es, bf_lo(us), ax);
        ay = fmaf(es, bf_hi(us), ay);
    }

    float2 bb = ((const float2*)b1)[lane];
    float2 ww = ((const float2*)W2)[lane];
    float r0 = fmaxf(fmaf(dw, ax, bb.x), 0.0f);
    float r1 = fmaxf(fmaf(dw, ay, bb.y), 0.0f);
    float v = r0 * ww.x + r1 * ww.y;
#pragma unroll
    for (int off = 32; off > 0; off >>= 1) v += __shfl_down(v, off);
    if (lane == 0) zs[w] = v * dw;
}

// ---------------- layer-2 aggregation + sigmoid epilogue: one thread per node ----------------
__global__ void k_agg2_final(const int* __restrict__ eidx,
                             const int* __restrict__ excl,
                             const int* __restrict__ chunkOff,
                             const int* __restrict__ cnt,
                             const float* __restrict__ zs,
                             const float* __restrict__ dinv,
                             const float* __restrict__ b2,
                             float* __restrict__ out) {
    int i = blockIdx.x * 256 + threadIdx.x;
    if (i >= NN) return;
    int offs = excl[i] + chunkOff[i >> 10];
    int c = cnt[i];
    float v = zs[i];   // self-loop
    for (int j = 0; j < c; ++j) v += zs[eidx[offs + j]];
    float z = fmaf(dinv[i], v, b2[0]);
    out[i] = 1.0f / (1.0f + __expf(-z));
}

extern "C" void kernel_launch(void* const* d_in, const int* in_sizes, int n_in,
                              void* d_out, int out_size, void* d_ws, size_t ws_size,
                              hipStream_t stream) {
    const float* x  = (const float*)d_in[0];
    const int*   ei = (const int*)d_in[1];
    const float* W1 = (const float*)d_in[2];
    const float* b1 = (const float*)d_in[3];
    const float* W2 = (const float*)d_in[4];
    const float* b2 = (const float*)d_in[5];
    float* out = (float*)d_out;

    const int E = in_sizes[1] / 2;
    const int* src = ei;
    const int* dst = ei + E;

    // workspace layout (4-byte elements)
    char* wsb = (char*)d_ws;
    float* dinv    = (float*)wsb;                       // N
    int*   cnt     = (int*)(dinv + NN);                 // N
    int*   cnt2    = cnt + NN;                          // N   (contiguous with cnt for memset)
    int*   excl    = cnt2 + NN;                         // N
    float* zs      = (float*)(excl + NN);               // N
    int*   chunkS  = (int*)(zs + NN);                   // 128
    int*   chunkO  = chunkS + 128;                      // 128
    int*   eidx    = chunkO + 128;                      // E
    unsigned short* hs = (unsigned short*)(eidx + E);   // N*128 bf16 (~25.6 MB)

    const int nb_nodes = (NN + 255) / 256;
    const int nb_edges = (E + 255) / 256;

    hipMemsetAsync(cnt, 0, (size_t)2 * NN * sizeof(int), stream);

    k_gemm_hist<<<GEMM_NB1 + nb_edges, 256, 0, stream>>>(x, W1, hs, dst, E, cnt);

    k_scan1d<<<NCHUNK, 256, 0, stream>>>(cnt, excl, chunkS, dinv);
    k_scan2<<<1, 128, 0, stream>>>(chunkS, chunkO);

    k_gemm_fill<<<GEMM_NB2 + nb_edges, 256, 0, stream>>>(x, W1, hs, src, dst, E,
                                                         excl, chunkO, cnt2, eidx);

    k_agg1l2<<<(NN * 64 + 255) / 256, 256, 0, stream>>>(eidx, excl, chunkO, cnt,
                                                        (const unsigned*)hs, dinv, b1, W2, zs);

    k_agg2_final<<<nb_nodes, 256, 0, stream>>>(eidx, excl, chunkO, cnt, zs, dinv, b2, out);
}